// Round 19
// baseline (629.518 us; speedup 1.0000x reference)
//
#include <hip/hip_runtime.h>

// ---------- types ----------
typedef __attribute__((ext_vector_type(8))) short bf16x8;
typedef __attribute__((ext_vector_type(8))) unsigned short u16x8;
typedef __attribute__((ext_vector_type(4))) float f32x4;
typedef __attribute__((ext_vector_type(2))) float f32x2;

__device__ __forceinline__ unsigned short f2bf(float f) {
  union { float f; unsigned u; } v; v.f = f;
  unsigned r = v.u + 0x7FFFu + ((v.u >> 16) & 1u);
  return (unsigned short)(r >> 16);
}
__device__ __forceinline__ float bf2f(unsigned short s) {
  union { unsigned u; float f; } v; v.u = ((unsigned)s) << 16;
  return v.f;
}
__device__ __forceinline__ float max3f(float a, float b, float c) {
  float d;
  asm("v_max3_f32 %0, %1, %2, %3" : "=v"(d) : "v"(a), "v"(b), "v"(c));
  return d;
}

template <int CTRL>
__device__ __forceinline__ float dpp_add(float v) {
  int m = __builtin_amdgcn_update_dpp(0, __float_as_int(v), CTRL, 0xf, 0xf, true);
  return v + __int_as_float(m);
}
__device__ __forceinline__ float wave_sum63(float v) {
  v = dpp_add<0x111>(v);
  v = dpp_add<0x112>(v);
  v = dpp_add<0x114>(v);
  v = dpp_add<0x118>(v);
  v = dpp_add<0x142>(v);
  v = dpp_add<0x143>(v);
  return v;
}

// Problem constants: B=64 T=512 E=300 V=50000 H=2048 WP=2 OUT=5
// padded: EP=320, TP=516, KP=1600, M=32768

// ---------- kernel 1: fused prep — W1 transpose-cast + embedding gather ----------
__global__ __launch_bounds__(256) void prep_kernel(
    const float* __restrict__ W1, unsigned short* __restrict__ W1bT,
    const int* __restrict__ idxs, const float* __restrict__ emb,
    unsigned short* __restrict__ P) {
  const int bid = blockIdx.x;
  const int tid = threadIdx.x;
  if (bid < 800) {
    __shared__ float tile[64][65];
    int kb = bid % 25;
    int hb = bid / 25;
    int win = kb / 5;
    int e0 = (kb % 5) << 6;
    int hh = tid & 63;
    int kq = tid >> 6;
#pragma unroll
    for (int kk = kq; kk < 64; kk += 4) {
      int e = e0 + kk;
      float v = 0.f;
      if (e < 300) v = W1[(size_t)(win * 300 + e) * 2048 + hb * 64 + hh];
      tile[kk][hh] = v;
    }
    __syncthreads();
    int kk = tid & 63;
    int hq = tid >> 6;
#pragma unroll
    for (int h = hq; h < 64; h += 4) {
      W1bT[(size_t)(hb * 64 + h) * 1600 + kb * 64 + kk] = f2bf(tile[kk][h]);
    }
    return;
  }
  int g4 = (bid - 800) * 4;
#pragma unroll
  for (int r = 0; r < 4; ++r) {
    int g = g4 + r;  // b*516+tp
    int b = g / 516;
    int tp = g - b * 516;
    int tok = 0;
    if (tp >= 2 && tp < 514) tok = idxs[b * 512 + tp - 2];
    const float* erow = emb + (size_t)tok * 300;
    float v = (tid < 300) ? erow[tid] : 0.f;
    P[(size_t)g * 320 + tid] = f2bf(v);
    if (tid < 64) {
      int e = tid + 256;
      float v2 = (e < 300) ? erow[e] : 0.f;
      P[(size_t)g * 320 + e] = f2bf(v2);
    }
  }
}

// ---------- kernel 2: GEMM  Z = A @ W1bT + b1  (bf16, f32 acc) ----------
// T2 both-sides swizzle + strength-reduced staging + LDS-transpose epilogue.
__global__ __launch_bounds__(256) void gemm_kernel(
    const unsigned short* __restrict__ P,
    const unsigned short* __restrict__ W1bT,
    const float* __restrict__ b1,
    unsigned short* __restrict__ Z) {
  __shared__ unsigned short smem[17408];  // staging + epilogue union
  unsigned short* As = smem;              // [128][64] swizzled slots
  unsigned short* Bs = smem + 8192;       // [128][64] swizzled slots
  const int tid = threadIdx.x;
  const int lane = tid & 63;
  const int w = tid >> 6;
  const int wm = w >> 1, wn = w & 1;
  const int lr = lane & 15;
  const int lk = (lane >> 4) << 3;

  const int nt = blockIdx.x & 15;
  const int mt = blockIdx.x >> 4;
  const int b = mt >> 2;
  const int t0 = (mt & 3) << 7;

  const unsigned short* srcA[4];
  const unsigned short* srcB[4];
#pragma unroll
  for (int j = 0; j < 4; ++j) {
    int chunk = tid + j * 256;
    int row = chunk >> 3, kb = chunk & 7;
    int kbs = kb ^ (row & 7);
    srcA[j] = P + (size_t)(b * 516 + t0 + row) * 320 + (kbs << 3);
    srcB[j] = W1bT + (size_t)(nt * 128 + row) * 1600 + (kbs << 3);
  }

  f32x4 acc[4][4];
#pragma unroll
  for (int i = 0; i < 4; i++)
#pragma unroll
    for (int j = 0; j < 4; j++) acc[i][j] = (f32x4){0.f, 0.f, 0.f, 0.f};

  for (int kt = 0; kt < 25; ++kt) {
#pragma unroll
    for (int j = 0; j < 4; ++j) {
      int chunk = tid + j * 256;
      __builtin_amdgcn_global_load_lds(
          (const __attribute__((address_space(1))) unsigned int*)srcA[j],
          (__attribute__((address_space(3))) unsigned int*)&As[chunk << 3],
          16, 0, 0);
      srcA[j] += 64;
    }
#pragma unroll
    for (int j = 0; j < 4; ++j) {
      int chunk = tid + j * 256;
      __builtin_amdgcn_global_load_lds(
          (const __attribute__((address_space(1))) unsigned int*)srcB[j],
          (__attribute__((address_space(3))) unsigned int*)&Bs[chunk << 3],
          16, 0, 0);
      srcB[j] += 64;
    }
    __syncthreads();
#pragma unroll
    for (int ks = 0; ks < 64; ks += 32) {
      const int slot = (ks + lk) >> 3;
      bf16x8 af[4], bv[4];
#pragma unroll
      for (int am = 0; am < 4; ++am) {
        int row = (wm << 6) + (am << 4) + lr;
        af[am] = *(const bf16x8*)&As[(row << 6) + ((slot ^ (row & 7)) << 3)];
      }
#pragma unroll
      for (int bn = 0; bn < 4; ++bn) {
        int col = (wn << 6) + (bn << 4) + lr;
        bv[bn] = *(const bf16x8*)&Bs[(col << 6) + ((slot ^ (col & 7)) << 3)];
      }
#pragma unroll
      for (int am = 0; am < 4; ++am)
#pragma unroll
        for (int bn = 0; bn < 4; ++bn)
          acc[am][bn] = __builtin_amdgcn_mfma_f32_16x16x32_bf16(
              af[am], bv[bn], acc[am][bn], 0, 0, 0);
    }
    __syncthreads();
  }

  // LDS-transpose epilogue (stride-136 bf16 tile -> coalesced dwordx4)
  {
    const int rq = lane >> 4;
    const int rloc0 = (wm << 6) + (rq << 2);
    const int cloc0 = (wn << 6) + lr;
    float b1v[4];
#pragma unroll
    for (int bn = 0; bn < 4; ++bn)
      b1v[bn] = b1[nt * 128 + cloc0 + (bn << 4)];
#pragma unroll
    for (int am = 0; am < 4; ++am)
#pragma unroll
      for (int bn = 0; bn < 4; ++bn) {
        int rl = rloc0 + (am << 4);
        int cl = cloc0 + (bn << 4);
#pragma unroll
        for (int j = 0; j < 4; ++j)
          smem[(rl + j) * 136 + cl] = f2bf(acc[am][bn][j] + b1v[bn]);
      }
    __syncthreads();
    const int chunk = tid & 15;
    const int rsub = tid >> 4;
#pragma unroll
    for (int p = 0; p < 8; ++p) {
      int row = p * 16 + rsub;
      u16x8 v = *(const u16x8*)&smem[row * 136 + chunk * 8];
      *(u16x8*)&Z[(size_t)(mt * 128 + row) * 2048 + nt * 128 + chunk * 8] = v;
    }
  }
}

// ---------- kernel 3: sequential scan — 2 waves (128 thr), 16 h/lane ----------
// r16 deferred-normalization structure; barrier narrowed to 2 waves and
// stage-B to 2 partials.  ~300 VGPR (1 wave/SIMD — the scan's natural
// occupancy anyway).
__global__ __launch_bounds__(128, 1) void scan_kernel(
    const unsigned short* __restrict__ Z, const float* __restrict__ W1,
    const float* __restrict__ W2, const float* __restrict__ b2,
    const float* __restrict__ istate, float* __restrict__ out) {
  const int b = blockIdx.x;
  const int tid = threadIdx.x;
  const int lane = tid & 63;
  const int wv = tid >> 6;  // 0..1
  const unsigned short* Zb = Z + (size_t)b * 512 * 2048;
  float* outb = out + (size_t)b * 512 * 5;

  // weights: 8 h-pairs per lane
  f32x2 w1p[8][10];
#pragma unroll
  for (int i = 0; i < 10; ++i) {
    const float* row = &W1[(size_t)(1500 + i) * 2048 + tid * 16];
#pragma unroll
    for (int q = 0; q < 8; ++q) w1p[q][i] = *(const f32x2*)&row[q * 2];
  }
  f32x2 w2p[8][5];
#pragma unroll
  for (int k = 0; k < 5; ++k)
#pragma unroll
    for (int q = 0; q < 8; ++q)
      w2p[q][k] = (f32x2){W2[(tid * 16 + 2 * q) * 5 + k],
                          W2[(tid * 16 + 2 * q + 1) * 5 + k]};
  const float b20 = b2[0], b21 = b2[1], b22 = b2[2], b23 = b2[3],
              b24 = b2[4];
  const float L2E = 1.4426950408889634f;

  __shared__ float part[2][2][8];
  __shared__ float out_lds[512][8];

  float ef0 = istate[5], ef1 = istate[6], ef2 = istate[7], ef3 = istate[8],
        ef4 = istate[9];
  float rf = 1.0f;

  // Z row: 32B/lane = two u16x8
  u16x8 zcA = *(const u16x8*)&Zb[tid * 16];
  u16x8 zcB = *(const u16x8*)&Zb[tid * 16 + 8];
  u16x8 znA = *(const u16x8*)&Zb[(size_t)2048 + tid * 16];
  u16x8 znB = *(const u16x8*)&Zb[(size_t)2048 + tid * 16 + 8];
  u16x8 zfA = *(const u16x8*)&Zb[(size_t)2 * 2048 + tid * 16];
  u16x8 zfB = *(const u16x8*)&Zb[(size_t)2 * 2048 + tid * 16 + 8];

  f32x2 xc[8];
#pragma unroll
  for (int q = 0; q < 4; ++q) {
    xc[q] = (f32x2){bf2f(zcA[2 * q]), bf2f(zcA[2 * q + 1])};
    xc[4 + q] = (f32x2){bf2f(zcB[2 * q]), bf2f(zcB[2 * q + 1])};
  }
#pragma unroll
  for (int i = 0; i < 5; ++i) {
    const float oi = istate[i];
#pragma unroll
    for (int q = 0; q < 8; ++q) xc[q] = oi * w1p[q][i] + xc[q];
  }

  for (int t = 0; t < 512; ++t) {
    // ---- stage A: fresh-half from unnormalized exps, late rf fold ----
    f32x2 x[8];
#pragma unroll
    for (int q = 0; q < 8; ++q) {
      f32x2 s = ef0 * w1p[q][5];
      s = ef1 * w1p[q][6] + s;
      s = ef2 * w1p[q][7] + s;
      s = ef3 * w1p[q][8] + s;
      s = ef4 * w1p[q][9] + s;
      x[q] = rf * s + xc[q];
      x[q] = __builtin_elementwise_max(x[q], (f32x2){0.f, 0.f});
    }
    f32x2 a0 = x[0] * w2p[0][0], a1 = x[0] * w2p[0][1],
          a2 = x[0] * w2p[0][2], a3 = x[0] * w2p[0][3],
          a4 = x[0] * w2p[0][4];
#pragma unroll
    for (int q = 1; q < 8; ++q) {
      a0 = x[q] * w2p[q][0] + a0;
      a1 = x[q] * w2p[q][1] + a1;
      a2 = x[q] * w2p[q][2] + a2;
      a3 = x[q] * w2p[q][3] + a3;
      a4 = x[q] * w2p[q][4] + a4;
    }
    float y0 = a0.x + a0.y, y1 = a1.x + a1.y, y2 = a2.x + a2.y,
          y3 = a3.x + a3.y, y4 = a4.x + a4.y;

    // prefetch row t+3
    int tn = (t + 3 < 512) ? (t + 3) : 511;
    u16x8 zfnA = *(const u16x8*)&Zb[(size_t)tn * 2048 + tid * 16];
    u16x8 zfnB = *(const u16x8*)&Zb[(size_t)tn * 2048 + tid * 16 + 8];

    // ---- intra-wave DPP reduce ----
    y0 = wave_sum63(y0);
    y1 = wave_sum63(y1);
    y2 = wave_sum63(y2);
    y3 = wave_sum63(y3);
    y4 = wave_sum63(y4);
    const int pp = t & 1;
    if (lane == 63) {
      *(float4*)&part[pp][wv][0] = (float4){y0, y1, y2, y3};
      part[pp][wv][4] = y4;
    }
    asm volatile("s_waitcnt lgkmcnt(0)" ::: "memory");
    __builtin_amdgcn_sched_barrier(0);
    __builtin_amdgcn_s_barrier();
    __builtin_amdgcn_sched_barrier(0);

    // ---- stage B: 2 partials + softmax, xnext fills the LDS shadow ----
    f32x4 q0 = *(const f32x4*)&part[pp][0][0];
    f32x4 q1 = *(const f32x4*)&part[pp][1][0];
    f32x4 sv = q0 + q1;
    float s4 = part[pp][0][4] + part[pp][1][4];
    float s0 = sv.x + b20, s1 = sv.y + b21, s2 = sv.z + b22,
          s3 = sv.w + b23;
    s4 += b24;

    // xnext for t+1 (stale half = rf*ef, late fold)
    f32x2 xe[8];
#pragma unroll
    for (int q = 0; q < 8; ++q) {
      f32x2 s = ef0 * w1p[q][0];
      s = ef1 * w1p[q][1] + s;
      s = ef2 * w1p[q][2] + s;
      s = ef3 * w1p[q][3] + s;
      s = ef4 * w1p[q][4] + s;
      xe[q] = s;
    }
#pragma unroll
    for (int q = 0; q < 4; ++q) {
      f32x2 za = (f32x2){bf2f(znA[2 * q]), bf2f(znA[2 * q + 1])};
      f32x2 zb = (f32x2){bf2f(znB[2 * q]), bf2f(znB[2 * q + 1])};
      xc[q] = rf * xe[q] + za;
      xc[4 + q] = rf * xe[4 + q] + zb;
    }

    if (tid == 0) {
      *(float4*)&out_lds[t][0] = (float4){s0, s1, s2, s3};
      out_lds[t][4] = s4;
    }

    float m = max3f(s0, s1, s2);
    m = max3f(m, s3, s4);
    float mL = m * L2E;
    ef0 = __builtin_amdgcn_exp2f(fmaf(s0, L2E, -mL));
    ef1 = __builtin_amdgcn_exp2f(fmaf(s1, L2E, -mL));
    ef2 = __builtin_amdgcn_exp2f(fmaf(s2, L2E, -mL));
    ef3 = __builtin_amdgcn_exp2f(fmaf(s3, L2E, -mL));
    ef4 = __builtin_amdgcn_exp2f(fmaf(s4, L2E, -mL));
    float d = ((ef0 + ef1) + (ef2 + ef3)) + ef4;
    rf = __builtin_amdgcn_rcpf(d);

    znA = zfA; znB = zfB;
    zfA = zfnA; zfB = zfnB;
  }

  __syncthreads();
  // cooperative store: thread tid owns steps 4*tid .. 4*tid+3 (20 floats)
  {
    float* dst = outb + tid * 20;
#pragma unroll
    for (int r = 0; r < 4; ++r) {
      const int row = tid * 4 + r;
#pragma unroll
      for (int i = 0; i < 5; ++i) dst[r * 5 + i] = out_lds[row][i];
    }
  }
}

// ---------- launcher ----------
extern "C" void kernel_launch(void* const* d_in, const int* in_sizes, int n_in,
                              void* d_out, int out_size, void* d_ws,
                              size_t ws_size, hipStream_t stream) {
  const int* idxs = (const int*)d_in[0];
  const float* emb = (const float*)d_in[1];
  const float* W1 = (const float*)d_in[2];
  const float* b1 = (const float*)d_in[3];
  const float* W2 = (const float*)d_in[4];
  const float* b2 = (const float*)d_in[5];
  const float* istate = (const float*)d_in[6];
  float* out = (float*)d_out;

  char* ws = (char*)d_ws;
  unsigned short* P = (unsigned short*)ws;                          // 21,135,360 B
  unsigned short* W1bT = (unsigned short*)(ws + 21135360);          // 6,553,600 B
  unsigned short* Z = (unsigned short*)(ws + 21135360 + 6553600);   // 134,217,728 B

  hipLaunchKernelGGL(prep_kernel, dim3(800 + 8256), dim3(256), 0, stream,
                     W1, W1bT, idxs, emb, P);
  hipLaunchKernelGGL(gemm_kernel, dim3(256 * 16), dim3(256), 0, stream, P, W1bT, b1, Z);
  hipLaunchKernelGGL(scan_kernel, dim3(64), dim3(128), 0, stream, Z, W1, W2, b2,
                     istate, out);
}

// Round 20
// 526.870 us; speedup vs baseline: 1.1948x; 1.1948x over previous
//
#include <hip/hip_runtime.h>

// ---------- types ----------
typedef __attribute__((ext_vector_type(8))) short bf16x8;
typedef __attribute__((ext_vector_type(8))) unsigned short u16x8;
typedef __attribute__((ext_vector_type(4))) float f32x4;
typedef __attribute__((ext_vector_type(2))) float f32x2;

__device__ __forceinline__ unsigned short f2bf(float f) {
  union { float f; unsigned u; } v; v.f = f;
  unsigned r = v.u + 0x7FFFu + ((v.u >> 16) & 1u);
  return (unsigned short)(r >> 16);
}
__device__ __forceinline__ float bf2f(unsigned short s) {
  union { unsigned u; float f; } v; v.u = ((unsigned)s) << 16;
  return v.f;
}
__device__ __forceinline__ float max3f(float a, float b, float c) {
  float d;
  asm("v_max3_f32 %0, %1, %2, %3" : "=v"(d) : "v"(a), "v"(b), "v"(c));
  return d;
}

template <int CTRL>
__device__ __forceinline__ float dpp_add(float v) {
  int m = __builtin_amdgcn_update_dpp(0, __float_as_int(v), CTRL, 0xf, 0xf, true);
  return v + __int_as_float(m);
}
__device__ __forceinline__ float wave_sum63(float v) {
  v = dpp_add<0x111>(v);
  v = dpp_add<0x112>(v);
  v = dpp_add<0x114>(v);
  v = dpp_add<0x118>(v);
  v = dpp_add<0x142>(v);
  v = dpp_add<0x143>(v);
  return v;
}

// Problem constants: B=64 T=512 E=300 V=50000 H=2048 WP=2 OUT=5
// padded: EP=320, TP=516, KP=1600, M=32768

// ---------- kernel 1: fused prep — W1 transpose-cast + embedding gather ----------
__global__ __launch_bounds__(256) void prep_kernel(
    const float* __restrict__ W1, unsigned short* __restrict__ W1bT,
    const int* __restrict__ idxs, const float* __restrict__ emb,
    unsigned short* __restrict__ P) {
  const int bid = blockIdx.x;
  const int tid = threadIdx.x;
  if (bid < 800) {
    __shared__ float tile[64][65];
    int kb = bid % 25;
    int hb = bid / 25;
    int win = kb / 5;
    int e0 = (kb % 5) << 6;
    int hh = tid & 63;
    int kq = tid >> 6;
#pragma unroll
    for (int kk = kq; kk < 64; kk += 4) {
      int e = e0 + kk;
      float v = 0.f;
      if (e < 300) v = W1[(size_t)(win * 300 + e) * 2048 + hb * 64 + hh];
      tile[kk][hh] = v;
    }
    __syncthreads();
    int kk = tid & 63;
    int hq = tid >> 6;
#pragma unroll
    for (int h = hq; h < 64; h += 4) {
      W1bT[(size_t)(hb * 64 + h) * 1600 + kb * 64 + kk] = f2bf(tile[kk][h]);
    }
    return;
  }
  int g4 = (bid - 800) * 4;
#pragma unroll
  for (int r = 0; r < 4; ++r) {
    int g = g4 + r;  // b*516+tp
    int b = g / 516;
    int tp = g - b * 516;
    int tok = 0;
    if (tp >= 2 && tp < 514) tok = idxs[b * 512 + tp - 2];
    const float* erow = emb + (size_t)tok * 300;
    float v = (tid < 300) ? erow[tid] : 0.f;
    P[(size_t)g * 320 + tid] = f2bf(v);
    if (tid < 64) {
      int e = tid + 256;
      float v2 = (e < 300) ? erow[e] : 0.f;
      P[(size_t)g * 320 + e] = f2bf(v2);
    }
  }
}

// ---------- kernel 2: GEMM  Z = A @ W1bT + b1  (bf16, f32 acc) ----------
// T2 both-sides swizzle + strength-reduced staging + LDS-transpose epilogue.
// NEW (r19): bijective XCD swizzle (T1) — 4096 blocks % 8 == 0, so
// bswz = (bid&7)*512 + (bid>>3) groups consecutive mt-tiles per XCD for
// A-panel L2 reuse.
__global__ __launch_bounds__(256) void gemm_kernel(
    const unsigned short* __restrict__ P,
    const unsigned short* __restrict__ W1bT,
    const float* __restrict__ b1,
    unsigned short* __restrict__ Z) {
  __shared__ unsigned short smem[17408];  // staging + epilogue union
  unsigned short* As = smem;              // [128][64] swizzled slots
  unsigned short* Bs = smem + 8192;       // [128][64] swizzled slots
  const int tid = threadIdx.x;
  const int lane = tid & 63;
  const int w = tid >> 6;
  const int wm = w >> 1, wn = w & 1;
  const int lr = lane & 15;
  const int lk = (lane >> 4) << 3;

  const int bid = blockIdx.x;
  const int bswz = (bid & 7) * 512 + (bid >> 3);  // bijective XCD swizzle
  const int nt = bswz & 15;
  const int mt = bswz >> 4;
  const int b = mt >> 2;
  const int t0 = (mt & 3) << 7;

  const unsigned short* srcA[4];
  const unsigned short* srcB[4];
#pragma unroll
  for (int j = 0; j < 4; ++j) {
    int chunk = tid + j * 256;
    int row = chunk >> 3, kb = chunk & 7;
    int kbs = kb ^ (row & 7);
    srcA[j] = P + (size_t)(b * 516 + t0 + row) * 320 + (kbs << 3);
    srcB[j] = W1bT + (size_t)(nt * 128 + row) * 1600 + (kbs << 3);
  }

  f32x4 acc[4][4];
#pragma unroll
  for (int i = 0; i < 4; i++)
#pragma unroll
    for (int j = 0; j < 4; j++) acc[i][j] = (f32x4){0.f, 0.f, 0.f, 0.f};

  for (int kt = 0; kt < 25; ++kt) {
#pragma unroll
    for (int j = 0; j < 4; ++j) {
      int chunk = tid + j * 256;
      __builtin_amdgcn_global_load_lds(
          (const __attribute__((address_space(1))) unsigned int*)srcA[j],
          (__attribute__((address_space(3))) unsigned int*)&As[chunk << 3],
          16, 0, 0);
      srcA[j] += 64;
    }
#pragma unroll
    for (int j = 0; j < 4; ++j) {
      int chunk = tid + j * 256;
      __builtin_amdgcn_global_load_lds(
          (const __attribute__((address_space(1))) unsigned int*)srcB[j],
          (__attribute__((address_space(3))) unsigned int*)&Bs[chunk << 3],
          16, 0, 0);
      srcB[j] += 64;
    }
    __syncthreads();
#pragma unroll
    for (int ks = 0; ks < 64; ks += 32) {
      const int slot = (ks + lk) >> 3;
      bf16x8 af[4], bv[4];
#pragma unroll
      for (int am = 0; am < 4; ++am) {
        int row = (wm << 6) + (am << 4) + lr;
        af[am] = *(const bf16x8*)&As[(row << 6) + ((slot ^ (row & 7)) << 3)];
      }
#pragma unroll
      for (int bn = 0; bn < 4; ++bn) {
        int col = (wn << 6) + (bn << 4) + lr;
        bv[bn] = *(const bf16x8*)&Bs[(col << 6) + ((slot ^ (col & 7)) << 3)];
      }
#pragma unroll
      for (int am = 0; am < 4; ++am)
#pragma unroll
        for (int bn = 0; bn < 4; ++bn)
          acc[am][bn] = __builtin_amdgcn_mfma_f32_16x16x32_bf16(
              af[am], bv[bn], acc[am][bn], 0, 0, 0);
    }
    __syncthreads();
  }

  // LDS-transpose epilogue (stride-136 bf16 tile -> coalesced dwordx4)
  {
    const int rq = lane >> 4;
    const int rloc0 = (wm << 6) + (rq << 2);
    const int cloc0 = (wn << 6) + lr;
    float b1v[4];
#pragma unroll
    for (int bn = 0; bn < 4; ++bn)
      b1v[bn] = b1[nt * 128 + cloc0 + (bn << 4)];
#pragma unroll
    for (int am = 0; am < 4; ++am)
#pragma unroll
      for (int bn = 0; bn < 4; ++bn) {
        int rl = rloc0 + (am << 4);
        int cl = cloc0 + (bn << 4);
#pragma unroll
        for (int j = 0; j < 4; ++j)
          smem[(rl + j) * 136 + cl] = f2bf(acc[am][bn][j] + b1v[bn]);
      }
    __syncthreads();
    const int chunk = tid & 15;
    const int rsub = tid >> 4;
#pragma unroll
    for (int p = 0; p < 8; ++p) {
      int row = p * 16 + rsub;
      u16x8 v = *(const u16x8*)&smem[row * 136 + chunk * 8];
      *(u16x8*)&Z[(size_t)(mt * 128 + row) * 2048 + nt * 128 + chunk * 8] = v;
    }
  }
}

// ---------- kernel 3: sequential scan — r16 4-wave body (measured floor) ----------
__global__ __launch_bounds__(256, 1) void scan_kernel(
    const unsigned short* __restrict__ Z, const float* __restrict__ W1,
    const float* __restrict__ W2, const float* __restrict__ b2,
    const float* __restrict__ istate, float* __restrict__ out) {
  const int b = blockIdx.x;
  const int tid = threadIdx.x;
  const int lane = tid & 63;
  const int wv = tid >> 6;  // 0..3
  const unsigned short* Zb = Z + (size_t)b * 512 * 2048;
  float* outb = out + (size_t)b * 512 * 5;

  f32x2 w1p[4][10];
#pragma unroll
  for (int i = 0; i < 10; ++i) {
    const float* row = &W1[(size_t)(1500 + i) * 2048 + tid * 8];
#pragma unroll
    for (int q = 0; q < 4; ++q) w1p[q][i] = *(const f32x2*)&row[q * 2];
  }
  f32x2 w2p[4][5];
#pragma unroll
  for (int k = 0; k < 5; ++k)
#pragma unroll
    for (int q = 0; q < 4; ++q)
      w2p[q][k] = (f32x2){W2[(tid * 8 + 2 * q) * 5 + k],
                          W2[(tid * 8 + 2 * q + 1) * 5 + k]};
  const float b20 = b2[0], b21 = b2[1], b22 = b2[2], b23 = b2[3],
              b24 = b2[4];
  const float L2E = 1.4426950408889634f;

  __shared__ float part[2][4][8];
  __shared__ float out_lds[512][8];

  float ef0 = istate[5], ef1 = istate[6], ef2 = istate[7], ef3 = istate[8],
        ef4 = istate[9];
  float rf = 1.0f;

  u16x8 zc0 = *(const u16x8*)&Zb[tid * 8];
  u16x8 zn = *(const u16x8*)&Zb[(size_t)2048 + tid * 8];
  u16x8 zf = *(const u16x8*)&Zb[(size_t)2 * 2048 + tid * 8];
  f32x2 xc[4];
  xc[0] = (f32x2){bf2f(zc0[0]), bf2f(zc0[1])};
  xc[1] = (f32x2){bf2f(zc0[2]), bf2f(zc0[3])};
  xc[2] = (f32x2){bf2f(zc0[4]), bf2f(zc0[5])};
  xc[3] = (f32x2){bf2f(zc0[6]), bf2f(zc0[7])};
#pragma unroll
  for (int i = 0; i < 5; ++i) {
    const float oi = istate[i];
#pragma unroll
    for (int q = 0; q < 4; ++q) xc[q] = oi * w1p[q][i] + xc[q];
  }

  for (int t = 0; t < 512; ++t) {
    f32x2 sA0 = ef0 * w1p[0][5], sA1 = ef0 * w1p[1][5],
          sA2 = ef0 * w1p[2][5], sA3 = ef0 * w1p[3][5];
    sA0 = ef1 * w1p[0][6] + sA0; sA1 = ef1 * w1p[1][6] + sA1;
    sA2 = ef1 * w1p[2][6] + sA2; sA3 = ef1 * w1p[3][6] + sA3;
    sA0 = ef2 * w1p[0][7] + sA0; sA1 = ef2 * w1p[1][7] + sA1;
    sA2 = ef2 * w1p[2][7] + sA2; sA3 = ef2 * w1p[3][7] + sA3;
    sA0 = ef3 * w1p[0][8] + sA0; sA1 = ef3 * w1p[1][8] + sA1;
    sA2 = ef3 * w1p[2][8] + sA2; sA3 = ef3 * w1p[3][8] + sA3;
    sA0 = ef4 * w1p[0][9] + sA0; sA1 = ef4 * w1p[1][9] + sA1;
    sA2 = ef4 * w1p[2][9] + sA2; sA3 = ef4 * w1p[3][9] + sA3;
    f32x2 x0 = rf * sA0 + xc[0];
    f32x2 x1 = rf * sA1 + xc[1];
    f32x2 x2 = rf * sA2 + xc[2];
    f32x2 x3 = rf * sA3 + xc[3];
    const f32x2 zero2 = (f32x2){0.f, 0.f};
    x0 = __builtin_elementwise_max(x0, zero2);
    x1 = __builtin_elementwise_max(x1, zero2);
    x2 = __builtin_elementwise_max(x2, zero2);
    x3 = __builtin_elementwise_max(x3, zero2);
    f32x2 a0 = x0 * w2p[0][0] + x1 * w2p[1][0];
    f32x2 a1 = x0 * w2p[0][1] + x1 * w2p[1][1];
    f32x2 a2 = x0 * w2p[0][2] + x1 * w2p[1][2];
    f32x2 a3 = x0 * w2p[0][3] + x1 * w2p[1][3];
    f32x2 a4 = x0 * w2p[0][4] + x1 * w2p[1][4];
    a0 = x2 * w2p[2][0] + a0;  a0 = x3 * w2p[3][0] + a0;
    a1 = x2 * w2p[2][1] + a1;  a1 = x3 * w2p[3][1] + a1;
    a2 = x2 * w2p[2][2] + a2;  a2 = x3 * w2p[3][2] + a2;
    a3 = x2 * w2p[2][3] + a3;  a3 = x3 * w2p[3][3] + a3;
    a4 = x2 * w2p[2][4] + a4;  a4 = x3 * w2p[3][4] + a4;
    float y0 = a0.x + a0.y, y1 = a1.x + a1.y, y2 = a2.x + a2.y,
          y3 = a3.x + a3.y, y4 = a4.x + a4.y;

    int tn = (t + 3 < 512) ? (t + 3) : 511;
    u16x8 zfn = *(const u16x8*)&Zb[(size_t)tn * 2048 + tid * 8];

    y0 = wave_sum63(y0);
    y1 = wave_sum63(y1);
    y2 = wave_sum63(y2);
    y3 = wave_sum63(y3);
    y4 = wave_sum63(y4);
    const int pp = t & 1;
    if (lane == 63) {
      *(float4*)&part[pp][wv][0] = (float4){y0, y1, y2, y3};
      part[pp][wv][4] = y4;
    }
    asm volatile("s_waitcnt lgkmcnt(0)" ::: "memory");
    __builtin_amdgcn_sched_barrier(0);
    __builtin_amdgcn_s_barrier();
    __builtin_amdgcn_sched_barrier(0);

    f32x4 q0 = *(const f32x4*)&part[pp][0][0];
    f32x4 q1 = *(const f32x4*)&part[pp][1][0];
    f32x4 q2 = *(const f32x4*)&part[pp][2][0];
    f32x4 q3 = *(const f32x4*)&part[pp][3][0];
    f32x4 sv = (q0 + q1) + (q2 + q3);
    float s4 = (part[pp][0][4] + part[pp][1][4]) +
               (part[pp][2][4] + part[pp][3][4]);
    float s0 = sv.x + b20, s1 = sv.y + b21, s2 = sv.z + b22,
          s3 = sv.w + b23;
    s4 += b24;

    f32x2 xe0 = ef0 * w1p[0][0], xe1 = ef0 * w1p[1][0],
          xe2 = ef0 * w1p[2][0], xe3 = ef0 * w1p[3][0];
    xe0 = ef1 * w1p[0][1] + xe0; xe1 = ef1 * w1p[1][1] + xe1;
    xe2 = ef1 * w1p[2][1] + xe2; xe3 = ef1 * w1p[3][1] + xe3;
    xe0 = ef2 * w1p[0][2] + xe0; xe1 = ef2 * w1p[1][2] + xe1;
    xe2 = ef2 * w1p[2][2] + xe2; xe3 = ef2 * w1p[3][2] + xe3;
    xe0 = ef3 * w1p[0][3] + xe0; xe1 = ef3 * w1p[1][3] + xe1;
    xe2 = ef3 * w1p[2][3] + xe2; xe3 = ef3 * w1p[3][3] + xe3;
    xe0 = ef4 * w1p[0][4] + xe0; xe1 = ef4 * w1p[1][4] + xe1;
    xe2 = ef4 * w1p[2][4] + xe2; xe3 = ef4 * w1p[3][4] + xe3;
    f32x2 zn0 = (f32x2){bf2f(zn[0]), bf2f(zn[1])};
    f32x2 zn1 = (f32x2){bf2f(zn[2]), bf2f(zn[3])};
    f32x2 zn2 = (f32x2){bf2f(zn[4]), bf2f(zn[5])};
    f32x2 zn3 = (f32x2){bf2f(zn[6]), bf2f(zn[7])};
    xc[0] = rf * xe0 + zn0;
    xc[1] = rf * xe1 + zn1;
    xc[2] = rf * xe2 + zn2;
    xc[3] = rf * xe3 + zn3;

    if (tid == 0) {
      *(float4*)&out_lds[t][0] = (float4){s0, s1, s2, s3};
      out_lds[t][4] = s4;
    }

    float m = max3f(s0, s1, s2);
    m = max3f(m, s3, s4);
    float mL = m * L2E;
    ef0 = __builtin_amdgcn_exp2f(fmaf(s0, L2E, -mL));
    ef1 = __builtin_amdgcn_exp2f(fmaf(s1, L2E, -mL));
    ef2 = __builtin_amdgcn_exp2f(fmaf(s2, L2E, -mL));
    ef3 = __builtin_amdgcn_exp2f(fmaf(s3, L2E, -mL));
    ef4 = __builtin_amdgcn_exp2f(fmaf(s4, L2E, -mL));
    float d = ((ef0 + ef1) + (ef2 + ef3)) + ef4;
    rf = __builtin_amdgcn_rcpf(d);

    zn = zf; zf = zfn;
  }

  __syncthreads();
  {
    const int r0 = tid * 2, r1 = tid * 2 + 1;
    float o[10];
#pragma unroll
    for (int i = 0; i < 5; ++i) o[i] = out_lds[r0][i];
#pragma unroll
    for (int i = 0; i < 5; ++i) o[5 + i] = out_lds[r1][i];
    float* dst = outb + tid * 10;
#pragma unroll
    for (int i = 0; i < 10; ++i) dst[i] = o[i];
  }
}

// ---------- launcher ----------
extern "C" void kernel_launch(void* const* d_in, const int* in_sizes, int n_in,
                              void* d_out, int out_size, void* d_ws,
                              size_t ws_size, hipStream_t stream) {
  const int* idxs = (const int*)d_in[0];
  const float* emb = (const float*)d_in[1];
  const float* W1 = (const float*)d_in[2];
  const float* b1 = (const float*)d_in[3];
  const float* W2 = (const float*)d_in[4];
  const float* b2 = (const float*)d_in[5];
  const float* istate = (const float*)d_in[6];
  float* out = (float*)d_out;

  char* ws = (char*)d_ws;
  unsigned short* P = (unsigned short*)ws;                          // 21,135,360 B
  unsigned short* W1bT = (unsigned short*)(ws + 21135360);          // 6,553,600 B
  unsigned short* Z = (unsigned short*)(ws + 21135360 + 6553600);   // 134,217,728 B

  hipLaunchKernelGGL(prep_kernel, dim3(800 + 8256), dim3(256), 0, stream,
                     W1, W1bT, idxs, emb, P);
  hipLaunchKernelGGL(gemm_kernel, dim3(256 * 16), dim3(256), 0, stream, P, W1bT, b1, Z);
  hipLaunchKernelGGL(scan_kernel, dim3(64), dim3(256), 0, stream, Z, W1, W2, b2,
                     istate, out);
}